// Round 1
// baseline (155.880 us; speedup 1.0000x reference)
//
#include <hip/hip_runtime.h>
#include <math.h>

#define NS2 0.70710678118654752440f  // 1/sqrt(2)
#define NS3 0.57735026918962576451f  // 1/sqrt(3)
#define NS6 0.40824829046386301636f  // 1/sqrt(6)

// ws layout (float offsets), every row padded to 8 floats (32B) for dwordx4 loads
#define OFF_G0   0        // [5120][8]   G0[c][k]  = sum_o W3_0[c,o] * Wout[o,k]
#define OFF_K1A  40960    // [3][2048][8] K1a[m][c][k] = sum_o W3_1[c,o]*Wout[64+o*3+m,k]
#define OFF_K1B  90112    // [3][2048][8] K1b[m][c][k] = sum_o W3_1[2048+c,o]*Wout[64+o*3+m,k]
#define OFF_K2   139264   // [5][1024][8] K2[m][c][k]  = sum_o W3_2[c,o]*Wout[160+o*5+m,k]
#define WS_FLOATS 180224  // 704 KB

__global__ __launch_bounds__(256) void precompute_kernel(
    const float* __restrict__ W3_0, const float* __restrict__ W3_1,
    const float* __restrict__ W3_2, const float* __restrict__ Wout,
    float* __restrict__ ws)
{
    int row = blockIdx.x * 256 + threadIdx.x;
    if (row >= 22528) return;
    float acc[7] = {0.f,0.f,0.f,0.f,0.f,0.f,0.f};
    float* dst;
    if (row < 5120) {
        const float* wr = W3_0 + row * 64;
        for (int o = 0; o < 64; ++o) {
            float wv = wr[o];
            const float* wo = Wout + o * 7;
            #pragma unroll
            for (int k = 0; k < 7; ++k) acc[k] = fmaf(wv, wo[k], acc[k]);
        }
        dst = ws + OFF_G0 + row * 8;
    } else if (row < 11264) {
        int t = row - 5120, m = t >> 11, c = t & 2047;
        const float* wr = W3_1 + c * 32;
        for (int o = 0; o < 32; ++o) {
            float wv = wr[o];
            const float* wo = Wout + (64 + o * 3 + m) * 7;
            #pragma unroll
            for (int k = 0; k < 7; ++k) acc[k] = fmaf(wv, wo[k], acc[k]);
        }
        dst = ws + OFF_K1A + t * 8;
    } else if (row < 17408) {
        int t = row - 11264, m = t >> 11, c = t & 2047;
        const float* wr = W3_1 + (2048 + c) * 32;
        for (int o = 0; o < 32; ++o) {
            float wv = wr[o];
            const float* wo = Wout + (64 + o * 3 + m) * 7;
            #pragma unroll
            for (int k = 0; k < 7; ++k) acc[k] = fmaf(wv, wo[k], acc[k]);
        }
        dst = ws + OFF_K1B + t * 8;
    } else {
        int t = row - 17408, m = t >> 10, c = t & 1023;
        const float* wr = W3_2 + c * 16;
        for (int o = 0; o < 16; ++o) {
            float wv = wr[o];
            const float* wo = Wout + (160 + o * 5 + m) * 7;
            #pragma unroll
            for (int k = 0; k < 7; ++k) acc[k] = fmaf(wv, wo[k], acc[k]);
        }
        dst = ws + OFF_K2 + t * 8;
    }
    #pragma unroll
    for (int k = 0; k < 7; ++k) dst[k] = acc[k];
    dst[7] = 0.f;
}

__device__ __forceinline__ void accum28(float acc[4][7], float4 av,
                                        const float rb[4],
                                        const float* __restrict__ row)
{
    float4 gA = *(const float4*)row;
    float4 gB = *(const float4*)(row + 4);
    float g[7] = {gA.x, gA.y, gA.z, gA.w, gB.x, gB.y, gB.z};
    float p[4] = {av.x * rb[0], av.y * rb[1], av.z * rb[2], av.w * rb[3]};
    #pragma unroll
    for (int j = 0; j < 4; ++j)
        #pragma unroll
        for (int k = 0; k < 7; ++k)
            acc[j][k] = fmaf(p[j], g[k], acc[j][k]);
}

// one wave handles 4 nodes; 4 waves/block; grid = N/16 blocks
__global__ __launch_bounds__(256) void main_kernel(
    const float* __restrict__ pos,
    const float* __restrict__ W1_0, const float* __restrict__ W1_1,
    const float* __restrict__ W2_0, const float* __restrict__ W2_1,
    const float* __restrict__ bout,
    const float* __restrict__ ws,
    float* __restrict__ out, int N)
{
    __shared__ float s_a0[4][64][4];   // [wave][a][node]
    __shared__ float s_A1[4][32][4];

    const int w    = threadIdx.x >> 6;
    const int lane = threadIdx.x & 63;
    const int base = blockIdx.x * 16 + w * 4;
    if (base >= N) return;

    // ---- per-node geometry + radial basis (lane c holds f0[c]; lanes<32 f1[c]) ----
    float dY[4], dZ[4], dX[4], dd[4], qq[5][4], f0r[4], f1r[4];
    #pragma unroll
    for (int j = 0; j < 4; ++j) {
        int n = base + j;
        float px = pos[n*3+0], py = pos[n*3+1], pz = pos[n*3+2];
        float r  = sqrtf(px*px + py*py + pz*pz) + 1e-9f;
        float iv = 1.0f / r;
        float d0 = py*iv, d1 = pz*iv, d2 = px*iv;      // (y,z,x) order
        dY[j]=d0; dZ[j]=d1; dX[j]=d2;
        dd[j] = d0*d0 + d1*d1 + d2*d2;                 // ~1 but keep exact
        qq[0][j] = 2.f*NS2*d2*d0;                      // sqrt2 * x*y
        qq[1][j] = 2.f*NS2*d0*d1;                      // sqrt2 * y*z
        qq[2][j] = NS6*(2.f*d1*d1 - d2*d2 - d0*d0);    // (2z^2-x^2-y^2)/sqrt6
        qq[3][j] = 2.f*NS2*d2*d1;                      // sqrt2 * x*z
        qq[4][j] = NS2*(d2*d2 - d0*d0);                // (x^2-y^2)/sqrt2
        float t0 = r - (5.0f/63.0f) * (float)lane;
        f0r[j] = __expf(-4.f * t0 * t0);
        float t1 = r - (5.0f/31.0f) * (float)lane;     // used only when lane<32
        f1r[j] = __expf(-4.f * t1 * t1);
    }
    #pragma unroll
    for (int j = 0; j < 4; ++j) s_a0[w][lane][j] = f0r[j];
    if (lane < 32) {
        #pragma unroll
        for (int j = 0; j < 4; ++j) s_A1[w][lane][j] = f1r[j];
    }
    __syncthreads();

    // ---- channel-mix matvecs: a0 = f0@W1_0, b0 = f0@W2_0, A1 = f1@W1_1, B1 = f1@W2_1 ----
    float a0r[4] = {0,0,0,0}, b0r[4] = {0,0,0,0}, v1r[4] = {0,0,0,0};
    {
        const float* wa = W1_0 + lane;
        const float* wb = W2_0 + lane;
        #pragma unroll 4
        for (int c = 0; c < 64; ++c) {
            float4 f = *(const float4*)&s_a0[w][c][0];
            float wav = wa[c*64], wbv = wb[c*64];
            a0r[0]=fmaf(f.x,wav,a0r[0]); a0r[1]=fmaf(f.y,wav,a0r[1]);
            a0r[2]=fmaf(f.z,wav,a0r[2]); a0r[3]=fmaf(f.w,wav,a0r[3]);
            b0r[0]=fmaf(f.x,wbv,b0r[0]); b0r[1]=fmaf(f.y,wbv,b0r[1]);
            b0r[2]=fmaf(f.z,wbv,b0r[2]); b0r[3]=fmaf(f.w,wbv,b0r[3]);
        }
        const float* wm = (lane < 32) ? (W1_1 + lane) : (W2_1 + (lane - 32));
        #pragma unroll 4
        for (int c = 0; c < 32; ++c) {
            float4 f = *(const float4*)&s_A1[w][c][0];
            float wv = wm[c*32];
            v1r[0]=fmaf(f.x,wv,v1r[0]); v1r[1]=fmaf(f.y,wv,v1r[1]);
            v1r[2]=fmaf(f.z,wv,v1r[2]); v1r[3]=fmaf(f.w,wv,v1r[3]);
        }
    }
    __syncthreads();
    #pragma unroll
    for (int j = 0; j < 4; ++j) s_a0[w][lane][j] = a0r[j];   // a0
    if (lane < 32) {
        #pragma unroll
        for (int j = 0; j < 4; ++j) s_A1[w][lane][j] = v1r[j]; // A1
    }
    __syncthreads();
    float B1r[4];   // B1[lane&31] for every lane (pulled from lanes 32..63)
    #pragma unroll
    for (int j = 0; j < 4; ++j) B1r[j] = __shfl(v1r[j], 32 + (lane & 31), 64);

    // ---- contraction phases: everything accumulates into one acc[4][7] ----
    float acc[4][7];
    #pragma unroll
    for (int j = 0; j < 4; ++j)
        #pragma unroll
        for (int k = 0; k < 7; ++k) acc[j][k] = 0.f;

    const int bh = lane & 31;
    const int ah = lane >> 5;

    // P1: 0x0->0, channels a*64+b (b = lane), weight G0[0:4096]
    {
        const float* sec = ws + OFF_G0;
        #pragma unroll 4
        for (int a = 0; a < 64; ++a) {
            float4 av = *(const float4*)&s_a0[w][a][0];
            accum28(acc, av, b0r, sec + (a*64 + lane)*8);
        }
    }
    // P2: 1x1->0, channels 4096 + a*32+b, scale S3*|d|^2
    {
        float rb[4];
        #pragma unroll
        for (int j = 0; j < 4; ++j) rb[j] = B1r[j] * (NS3 * dd[j]);
        const float* sec = ws + OFF_G0 + 4096*8;
        #pragma unroll 4
        for (int a2 = 0; a2 < 16; ++a2) {
            int a = ah*16 + a2;
            float4 av = *(const float4*)&s_A1[w][a][0];
            accum28(acc, av, rb, sec + (a*32 + bh)*8);
        }
    }
    // P3/P4: l=1 outputs, d_m folded into rb; m = 0(y),1(z),2(x)
    #pragma unroll
    for (int m = 0; m < 3; ++m) {
        float dm[4];
        #pragma unroll
        for (int j = 0; j < 4; ++j) dm[j] = (m==0) ? dY[j] : (m==1 ? dZ[j] : dX[j]);
        {   // 0x1->1 : a0[a] * B1[b], c = a*32+b
            float rb[4];
            #pragma unroll
            for (int j = 0; j < 4; ++j) rb[j] = B1r[j] * dm[j];
            const float* sec = ws + OFF_K1A + m*2048*8;
            #pragma unroll 4
            for (int a2 = 0; a2 < 32; ++a2) {
                int a = ah*32 + a2;
                float4 av = *(const float4*)&s_a0[w][a][0];
                accum28(acc, av, rb, sec + (a*32 + bh)*8);
            }
        }
        {   // 1x0->1 : A1[a] * b0[b], c = a*64+b (b = lane)
            float rb[4];
            #pragma unroll
            for (int j = 0; j < 4; ++j) rb[j] = b0r[j] * dm[j];
            const float* sec = ws + OFF_K1B + m*2048*8;
            #pragma unroll 4
            for (int a = 0; a < 32; ++a) {
                float4 av = *(const float4*)&s_A1[w][a][0];
                accum28(acc, av, rb, sec + (a*64 + lane)*8);
            }
        }
    }
    // P5: 1x1->2, q_m folded into rb; c = a*32+b
    #pragma unroll
    for (int m = 0; m < 5; ++m) {
        float rb[4];
        #pragma unroll
        for (int j = 0; j < 4; ++j) rb[j] = B1r[j] * qq[m][j];
        const float* sec = ws + OFF_K2 + m*1024*8;
        #pragma unroll 4
        for (int a2 = 0; a2 < 16; ++a2) {
            int a = ah*16 + a2;
            float4 av = *(const float4*)&s_A1[w][a][0];
            accum28(acc, av, rb, sec + (a*32 + bh)*8);
        }
    }

    // ---- wave reduction (64 lanes) + output ----
    #pragma unroll
    for (int j = 0; j < 4; ++j)
        #pragma unroll
        for (int k = 0; k < 7; ++k) {
            float v = acc[j][k];
            v += __shfl_xor(v, 1, 64);
            v += __shfl_xor(v, 2, 64);
            v += __shfl_xor(v, 4, 64);
            v += __shfl_xor(v, 8, 64);
            v += __shfl_xor(v, 16, 64);
            v += __shfl_xor(v, 32, 64);
            acc[j][k] = v;
        }
    if (lane == 0) {
        #pragma unroll
        for (int j = 0; j < 4; ++j)
            #pragma unroll
            for (int k = 0; k < 7; ++k)
                out[(base + j)*7 + k] = acc[j][k] + bout[k];
    }
}

extern "C" void kernel_launch(void* const* d_in, const int* in_sizes, int n_in,
                              void* d_out, int out_size, void* d_ws, size_t ws_size,
                              hipStream_t stream)
{
    const float* pos  = (const float*)d_in[0];
    const float* W1_0 = (const float*)d_in[1];
    const float* W1_1 = (const float*)d_in[2];
    const float* W2_0 = (const float*)d_in[3];
    const float* W2_1 = (const float*)d_in[4];
    const float* W3_0 = (const float*)d_in[5];
    const float* W3_1 = (const float*)d_in[6];
    const float* W3_2 = (const float*)d_in[7];
    const float* Wout = (const float*)d_in[8];
    const float* bout = (const float*)d_in[9];
    float* ws  = (float*)d_ws;
    float* op  = (float*)d_out;
    int N = in_sizes[0] / 3;   // 4096

    precompute_kernel<<<(22528 + 255)/256, 256, 0, stream>>>(W3_0, W3_1, W3_2, Wout, ws);
    main_kernel<<<(N + 15)/16, 256, 0, stream>>>(pos, W1_0, W1_1, W2_0, W2_1, bout, ws, op, N);
}

// Round 2
// 121.638 us; speedup vs baseline: 1.2815x; 1.2815x over previous
//
#include <hip/hip_runtime.h>
#include <math.h>

#define NS2 0.70710678118654752440f  // 1/sqrt(2)
#define NS3 0.57735026918962576451f  // 1/sqrt(3)
#define NS6 0.40824829046386301636f  // 1/sqrt(6)

// ws layout (float offsets), every row padded to 8 floats (32B) for dwordx4 loads
#define OFF_G0   0        // [5120][8]   G0[c][k]  = sum_o W3_0[c,o] * Wout[o,k]
#define OFF_K1A  40960    // [3][2048][8] K1a[m][c][k] = sum_o W3_1[c,o]*Wout[64+o*3+m,k]
#define OFF_K1B  90112    // [3][2048][8] K1b[m][c][k] = sum_o W3_1[2048+c,o]*Wout[64+o*3+m,k]
#define OFF_K2   139264   // [5][1024][8] K2[m][c][k]  = sum_o W3_2[c,o]*Wout[160+o*5+m,k]

__global__ __launch_bounds__(256) void precompute_kernel(
    const float* __restrict__ W3_0, const float* __restrict__ W3_1,
    const float* __restrict__ W3_2, const float* __restrict__ Wout,
    float* __restrict__ ws)
{
    __shared__ float s_wo[1680];           // Wout is 240x7
    for (int i = threadIdx.x; i < 1680; i += 256) s_wo[i] = Wout[i];
    __syncthreads();

    int row = blockIdx.x * 256 + threadIdx.x;
    if (row >= 22528) return;
    float acc[7] = {0.f,0.f,0.f,0.f,0.f,0.f,0.f};
    float* dst;
    if (row < 5120) {
        const float* wr = W3_0 + row * 64;
        #pragma unroll 4
        for (int o = 0; o < 64; o += 4) {
            float4 wv = *(const float4*)(wr + o);
            const float* w0 = s_wo + o * 7;          // stride 7 per o
            #pragma unroll
            for (int k = 0; k < 7; ++k)
                acc[k] = fmaf(wv.x, w0[k],
                         fmaf(wv.y, w0[7+k],
                         fmaf(wv.z, w0[14+k],
                         fmaf(wv.w, w0[21+k], acc[k]))));
        }
        dst = ws + OFF_G0 + row * 8;
    } else if (row < 11264) {
        int t = row - 5120, m = t >> 11, c = t & 2047;
        const float* wr = W3_1 + c * 32;
        #pragma unroll 4
        for (int o = 0; o < 32; o += 4) {
            float4 wv = *(const float4*)(wr + o);
            const float* w0 = s_wo + (64 + o*3 + m) * 7;  // stride 21 per o
            #pragma unroll
            for (int k = 0; k < 7; ++k)
                acc[k] = fmaf(wv.x, w0[k],
                         fmaf(wv.y, w0[21+k],
                         fmaf(wv.z, w0[42+k],
                         fmaf(wv.w, w0[63+k], acc[k]))));
        }
        dst = ws + OFF_K1A + t * 8;
    } else if (row < 17408) {
        int t = row - 11264, m = t >> 11, c = t & 2047;
        const float* wr = W3_1 + (2048 + c) * 32;
        #pragma unroll 4
        for (int o = 0; o < 32; o += 4) {
            float4 wv = *(const float4*)(wr + o);
            const float* w0 = s_wo + (64 + o*3 + m) * 7;
            #pragma unroll
            for (int k = 0; k < 7; ++k)
                acc[k] = fmaf(wv.x, w0[k],
                         fmaf(wv.y, w0[21+k],
                         fmaf(wv.z, w0[42+k],
                         fmaf(wv.w, w0[63+k], acc[k]))));
        }
        dst = ws + OFF_K1B + t * 8;
    } else {
        int t = row - 17408, m = t >> 10, c = t & 1023;
        const float* wr = W3_2 + c * 16;
        #pragma unroll 4
        for (int o = 0; o < 16; o += 4) {
            float4 wv = *(const float4*)(wr + o);
            const float* w0 = s_wo + (160 + o*5 + m) * 7;  // stride 35 per o
            #pragma unroll
            for (int k = 0; k < 7; ++k)
                acc[k] = fmaf(wv.x, w0[k],
                         fmaf(wv.y, w0[35+k],
                         fmaf(wv.z, w0[70+k],
                         fmaf(wv.w, w0[105+k], acc[k]))));
        }
        dst = ws + OFF_K2 + t * 8;
    }
    *(float4*)dst       = make_float4(acc[0], acc[1], acc[2], acc[3]);
    *(float4*)(dst + 4) = make_float4(acc[4], acc[5], acc[6], 0.f);
}

__device__ __forceinline__ void accum8(float acc[8][7],
                                       const float* __restrict__ av8,  // LDS row, 8 floats
                                       const float rb[8],
                                       const float* __restrict__ row)  // weight row, 8 floats
{
    float4 gA = *(const float4*)row;
    float4 gB = *(const float4*)(row + 4);
    float g[7] = {gA.x, gA.y, gA.z, gA.w, gB.x, gB.y, gB.z};
    float4 a0v = *(const float4*)av8;
    float4 a1v = *(const float4*)(av8 + 4);
    float av[8] = {a0v.x, a0v.y, a0v.z, a0v.w, a1v.x, a1v.y, a1v.z, a1v.w};
    #pragma unroll
    for (int j = 0; j < 8; ++j) {
        float p = av[j] * rb[j];
        #pragma unroll
        for (int k = 0; k < 7; ++k) acc[j][k] = fmaf(p, g[k], acc[j][k]);
    }
}

// block = 256 threads (4 waves) handles 8 nodes; waves split channel space 4-way
__global__ __launch_bounds__(256) void main_kernel(
    const float* __restrict__ pos,
    const float* __restrict__ W1_0, const float* __restrict__ W1_1,
    const float* __restrict__ W2_0, const float* __restrict__ W2_1,
    const float* __restrict__ bout,
    const float* __restrict__ ws,
    float* __restrict__ out, int N)
{
    __shared__ float s_f0[8][64];
    __shared__ float s_f1[8][32];
    __shared__ float s_a0[64][8];
    __shared__ float s_b0[64][8];
    __shared__ float s_A1[32][8];
    __shared__ float s_B1[32][8];
    __shared__ float s_geom[8][9];   // dY,dZ,dX, NS3*|d|^2, qq[0..4]
    __shared__ float s_red[4][56];

    const int tid  = threadIdx.x;
    const int w    = tid >> 6;
    const int lane = tid & 63;
    const int base = blockIdx.x * 8;

    // ---- step 1: radial basis into LDS; geometry for 8 nodes ----
    {
        int d = tid & 63;
        #pragma unroll
        for (int jj = 0; jj < 2; ++jj) {
            int j = (tid >> 6) + jj * 4;
            int n = base + j;
            float px = pos[n*3+0], py = pos[n*3+1], pz = pos[n*3+2];
            float r  = sqrtf(px*px + py*py + pz*pz) + 1e-9f;
            float t0 = r - (5.0f/63.0f) * (float)d;
            s_f0[j][d] = __expf(-4.f * t0 * t0);
        }
        {
            int j = tid >> 5, d1 = tid & 31;
            int n = base + j;
            float px = pos[n*3+0], py = pos[n*3+1], pz = pos[n*3+2];
            float r  = sqrtf(px*px + py*py + pz*pz) + 1e-9f;
            float t1 = r - (5.0f/31.0f) * (float)d1;
            s_f1[j][d1] = __expf(-4.f * t1 * t1);
        }
        if (tid < 8) {
            int n = base + tid;
            float px = pos[n*3+0], py = pos[n*3+1], pz = pos[n*3+2];
            float r  = sqrtf(px*px + py*py + pz*pz) + 1e-9f;
            float iv = 1.0f / r;
            float d0 = py*iv, d1 = pz*iv, d2 = px*iv;       // (y,z,x)
            s_geom[tid][0] = d0;
            s_geom[tid][1] = d1;
            s_geom[tid][2] = d2;
            s_geom[tid][3] = NS3 * (d0*d0 + d1*d1 + d2*d2);
            s_geom[tid][4] = 2.f*NS2*d2*d0;
            s_geom[tid][5] = 2.f*NS2*d0*d1;
            s_geom[tid][6] = NS6*(2.f*d1*d1 - d2*d2 - d0*d0);
            s_geom[tid][7] = 2.f*NS2*d2*d1;
            s_geom[tid][8] = NS2*(d2*d2 - d0*d0);
        }
    }
    __syncthreads();

    // ---- step 2: channel-mix matvecs ----
    {
        int c = tid & 63, jb = tid >> 6;       // this thread: a0/b0 for (c, jb) and (c, jb+4)
        float aa0 = 0.f, aa1 = 0.f, ba0 = 0.f, ba1 = 0.f;
        const float* wa = W1_0 + c;
        const float* wb = W2_0 + c;
        #pragma unroll 4
        for (int d = 0; d < 64; ++d) {
            float wav = wa[d*64], wbv = wb[d*64];
            float fA = s_f0[jb][d], fB = s_f0[jb+4][d];
            aa0 = fmaf(fA, wav, aa0);  aa1 = fmaf(fB, wav, aa1);
            ba0 = fmaf(fA, wbv, ba0);  ba1 = fmaf(fB, wbv, ba1);
        }
        s_a0[c][jb] = aa0;  s_a0[c][jb+4] = aa1;
        s_b0[c][jb] = ba0;  s_b0[c][jb+4] = ba1;

        int c1 = tid & 31, j8 = tid >> 5;      // A1/B1 for (c1, j8)
        float aA = 0.f, aB = 0.f;
        const float* wA = W1_1 + c1;
        const float* wB = W2_1 + c1;
        #pragma unroll 4
        for (int d = 0; d < 32; ++d) {
            float f = s_f1[j8][d];
            aA = fmaf(f, wA[d*32], aA);
            aB = fmaf(f, wB[d*32], aB);
        }
        s_A1[c1][j8] = aA;  s_B1[c1][j8] = aB;
    }
    __syncthreads();

    // ---- step 3: per-lane B-side registers ----
    const int bh = lane & 31, ah = lane >> 5;
    float b0r[8], B1r[8];
    {
        float4 t0 = *(const float4*)&s_b0[lane][0];
        float4 t1 = *(const float4*)&s_b0[lane][4];
        b0r[0]=t0.x; b0r[1]=t0.y; b0r[2]=t0.z; b0r[3]=t0.w;
        b0r[4]=t1.x; b0r[5]=t1.y; b0r[6]=t1.z; b0r[7]=t1.w;
        float4 u0 = *(const float4*)&s_B1[bh][0];
        float4 u1 = *(const float4*)&s_B1[bh][4];
        B1r[0]=u0.x; B1r[1]=u0.y; B1r[2]=u0.z; B1r[3]=u0.w;
        B1r[4]=u1.x; B1r[5]=u1.y; B1r[6]=u1.z; B1r[7]=u1.w;
    }

    float acc[8][7];
    #pragma unroll
    for (int j = 0; j < 8; ++j)
        #pragma unroll
        for (int k = 0; k < 7; ++k) acc[j][k] = 0.f;

    // ---- P1: 0x0->0, b = lane, a = w*16 + i ----
    {
        const float* sec = ws + OFF_G0;
        #pragma unroll 2
        for (int i = 0; i < 16; ++i) {
            int a = w*16 + i;
            accum8(acc, &s_a0[a][0], b0r, sec + (a*64 + lane)*8);
        }
    }
    // ---- P2: 1x1->0, b = bh, a = ah*16 + w*4 + i ----
    {
        float rb[8];
        #pragma unroll
        for (int j = 0; j < 8; ++j) rb[j] = B1r[j] * s_geom[j][3];
        const float* sec = ws + OFF_G0 + 4096*8;
        #pragma unroll 2
        for (int i = 0; i < 4; ++i) {
            int a = ah*16 + w*4 + i;
            accum8(acc, &s_A1[a][0], rb, sec + (a*32 + bh)*8);
        }
    }
    // ---- P3: 0x1->1 (K1a), m in {y,z,x}; a = ah*32 + w*8 + i ----
    #pragma unroll
    for (int m = 0; m < 3; ++m) {
        float rb[8];
        #pragma unroll
        for (int j = 0; j < 8; ++j) rb[j] = B1r[j] * s_geom[j][m];
        const float* sec = ws + OFF_K1A + m*2048*8;
        #pragma unroll 2
        for (int i = 0; i < 8; ++i) {
            int a = ah*32 + w*8 + i;
            accum8(acc, &s_a0[a][0], rb, sec + (a*32 + bh)*8);
        }
    }
    // ---- P4: 1x0->1 (K1b), b = lane, a = w*8 + i ----
    #pragma unroll
    for (int m = 0; m < 3; ++m) {
        float rb[8];
        #pragma unroll
        for (int j = 0; j < 8; ++j) rb[j] = b0r[j] * s_geom[j][m];
        const float* sec = ws + OFF_K1B + m*2048*8;
        #pragma unroll 2
        for (int i = 0; i < 8; ++i) {
            int a = w*8 + i;
            accum8(acc, &s_A1[a][0], rb, sec + (a*64 + lane)*8);
        }
    }
    // ---- P5: 1x1->2 (K2), a = ah*16 + w*4 + i ----
    #pragma unroll
    for (int m = 0; m < 5; ++m) {
        float rb[8];
        #pragma unroll
        for (int j = 0; j < 8; ++j) rb[j] = B1r[j] * s_geom[j][4+m];
        const float* sec = ws + OFF_K2 + m*1024*8;
        #pragma unroll 2
        for (int i = 0; i < 4; ++i) {
            int a = ah*16 + w*4 + i;
            accum8(acc, &s_A1[a][0], rb, sec + (a*32 + bh)*8);
        }
    }

    // ---- reduce across 64 lanes, then across 4 waves ----
    #pragma unroll
    for (int j = 0; j < 8; ++j)
        #pragma unroll
        for (int k = 0; k < 7; ++k) {
            float v = acc[j][k];
            v += __shfl_xor(v, 1, 64);
            v += __shfl_xor(v, 2, 64);
            v += __shfl_xor(v, 4, 64);
            v += __shfl_xor(v, 8, 64);
            v += __shfl_xor(v, 16, 64);
            v += __shfl_xor(v, 32, 64);
            acc[j][k] = v;
        }
    if (lane == 0) {
        #pragma unroll
        for (int j = 0; j < 8; ++j)
            #pragma unroll
            for (int k = 0; k < 7; ++k)
                s_red[w][j*7 + k] = acc[j][k];
    }
    __syncthreads();
    if (tid < 56) {
        int j = tid / 7, k = tid % 7;
        float v = s_red[0][tid] + s_red[1][tid] + s_red[2][tid] + s_red[3][tid] + bout[k];
        out[(base + j)*7 + k] = v;
    }
}

extern "C" void kernel_launch(void* const* d_in, const int* in_sizes, int n_in,
                              void* d_out, int out_size, void* d_ws, size_t ws_size,
                              hipStream_t stream)
{
    const float* pos  = (const float*)d_in[0];
    const float* W1_0 = (const float*)d_in[1];
    const float* W1_1 = (const float*)d_in[2];
    const float* W2_0 = (const float*)d_in[3];
    const float* W2_1 = (const float*)d_in[4];
    const float* W3_0 = (const float*)d_in[5];
    const float* W3_1 = (const float*)d_in[6];
    const float* W3_2 = (const float*)d_in[7];
    const float* Wout = (const float*)d_in[8];
    const float* bout = (const float*)d_in[9];
    float* ws  = (float*)d_ws;
    float* op  = (float*)d_out;
    int N = in_sizes[0] / 3;   // 4096

    precompute_kernel<<<88, 256, 0, stream>>>(W3_0, W3_1, W3_2, Wout, ws);
    main_kernel<<<N / 8, 256, 0, stream>>>(pos, W1_0, W1_1, W2_0, W2_1, bout, ws, op, N);
}